// Round 5
// baseline (648.054 us; speedup 1.0000x reference)
//
#include <hip/hip_runtime.h>

typedef unsigned short u16;
typedef unsigned int u32;
typedef __attribute__((ext_vector_type(8))) __bf16 bf16x8;
typedef __attribute__((ext_vector_type(4))) float f32x4;
typedef __attribute__((ext_vector_type(2))) u32 u32x2;
typedef __attribute__((ext_vector_type(4))) u32 u32x4;

__device__ __forceinline__ u16 f2bf(float f) {
    u32 u = __float_as_uint(f);
    u = (u + 0x7FFFu + ((u >> 16) & 1u)) >> 16;
    return (u16)u;
}

// native casts -> v_cvt_pk_bf16_f32 (RNE)
__device__ __forceinline__ bf16x8 load8f_bf(const float* p) {
    f32x4 f0 = *(const f32x4*)p;
    f32x4 f1 = *(const f32x4*)(p + 4);
    bf16x8 r;
    r[0] = (__bf16)f0[0]; r[1] = (__bf16)f0[1]; r[2] = (__bf16)f0[2]; r[3] = (__bf16)f0[3];
    r[4] = (__bf16)f1[0]; r[5] = (__bf16)f1[1]; r[6] = (__bf16)f1[2]; r[7] = (__bf16)f1[3];
    return r;
}
__device__ __forceinline__ bf16x8 cvt2bf(f32x4 lo, f32x4 hi) {
    bf16x8 r;
    r[0] = (__bf16)lo[0]; r[1] = (__bf16)lo[1]; r[2] = (__bf16)lo[2]; r[3] = (__bf16)lo[3];
    r[4] = (__bf16)hi[0]; r[5] = (__bf16)hi[1]; r[6] = (__bf16)hi[2]; r[7] = (__bf16)hi[3];
    return r;
}
__device__ __forceinline__ u32 pk2(float x, float y) {
    __bf16 bx = (__bf16)x, by = (__bf16)y;
    return (u32)__builtin_bit_cast(u16, bx) | ((u32)__builtin_bit_cast(u16, by) << 16);
}

// packed A-fragment (W^T) layout, per layer: idx = ((s*4 + m)*64 + lane)*8 + j
// value = W[k][16*m + (lane&15)], k = s*32 + (lane>>4)*8 + j
#define PK_EW1 0
#define PK_EW2 12288
#define PK_EW3 16384
#define PK_NW1 20480
#define PK_NW2 28672
#define PK_NW3 32768
#define PK_TOTAL 36864

__global__ void pack_weights_kernel(const float* __restrict__ eW1, const float* __restrict__ eW2,
                                    const float* __restrict__ eW3, const float* __restrict__ nW1,
                                    const float* __restrict__ nW2, const float* __restrict__ nW3,
                                    u16* __restrict__ P) {
    int idx = blockIdx.x * blockDim.x + threadIdx.x;
    if (idx >= PK_TOTAL) return;
    const float* W; int base;
    if (idx < PK_EW2)      { W = eW1; base = PK_EW1; }
    else if (idx < PK_EW3) { W = eW2; base = PK_EW2; }
    else if (idx < PK_NW1) { W = eW3; base = PK_EW3; }
    else if (idx < PK_NW2) { W = nW1; base = PK_NW1; }
    else if (idx < PK_NW3) { W = nW2; base = PK_NW2; }
    else                   { W = nW3; base = PK_NW3; }
    int r = idx - base;
    int j = r & 7, lane = (r >> 3) & 63, m = (r >> 9) & 3, s = r >> 11;
    int k = s * 32 + (lane >> 4) * 8 + j;
    int col = 16 * m + (lane & 15);
    P[idx] = f2bf(W[k * 64 + col]);
}

// ---------------- CSR build ----------------
__global__ void degree_kernel(const int* __restrict__ edge_idx, int* __restrict__ deg, int E) {
    int e = blockIdx.x * blockDim.x + threadIdx.x;
    if (e < E) atomicAdd(&deg[edge_idx[2 * e]], 1);
}

__global__ void scan_blocks_kernel(const int* __restrict__ deg, int* __restrict__ off,
                                   int* __restrict__ partials, int N) {
    __shared__ int sh[256];
    const int t = threadIdx.x;
    const int g = blockIdx.x * 256 + t;
    int v = (g < N) ? deg[g] : 0;
    sh[t] = v;
    __syncthreads();
#pragma unroll
    for (int d = 1; d < 256; d <<= 1) {
        int add = (t >= d) ? sh[t - d] : 0;
        __syncthreads();
        sh[t] += add;
        __syncthreads();
    }
    if (g < N) off[g] = sh[t] - v;
    if (t == 255) partials[blockIdx.x] = sh[255];
}

__global__ void scan_partials_kernel(int* __restrict__ partials, int nparts) {
    __shared__ int sh[256];
    const int t = threadIdx.x;
    int v = (t < nparts) ? partials[t] : 0;
    sh[t] = v;
    __syncthreads();
#pragma unroll
    for (int d = 1; d < 256; d <<= 1) {
        int add = (t >= d) ? sh[t - d] : 0;
        __syncthreads();
        sh[t] += add;
        __syncthreads();
    }
    if (t < nparts) partials[t] = sh[t] - v;
}

__global__ void finalize_offsets_kernel(int* __restrict__ off, int* __restrict__ pos,
                                        const int* __restrict__ partials, int N, int E) {
    int g = blockIdx.x * blockDim.x + threadIdx.x;
    if (g < N) {
        int o = off[g] + partials[g >> 8];
        off[g] = o;
        pos[g] = o;
    }
    if (g == 0) off[N] = E;
}

__global__ void fill_csr_kernel(const int* __restrict__ edge_idx, int* __restrict__ pos,
                                int* __restrict__ csr, int E) {
    int e = blockIdx.x * blockDim.x + threadIdx.x;
    if (e < E) {
        int slot = atomicAdd(&pos[edge_idx[2 * e]], 1);
        csr[slot] = e;
    }
}

// ---------------- edge MLP + LN: 32 edges/wave, single 2KB LDS tile per wave ----------------
#define ET 2
__global__ __launch_bounds__(256) void edge_mlp_kernel(
    const float* __restrict__ node_feat, const float* __restrict__ edge_feat,
    const int* __restrict__ edge_idx, const u16* __restrict__ Pw,
    const float* __restrict__ b1g, const float* __restrict__ b2g, const float* __restrict__ b3g,
    const float* __restrict__ gg, const float* __restrict__ betag,
    float* __restrict__ out_edge, int E)
{
    __shared__ float params[5][64];
    __shared__ u16 htile[4][1024];  // ONE 16x64 bf16 tile per wave, XOR-swizzled, reused
    const int tid = threadIdx.x;
    if (tid < 64) {
        params[0][tid] = b1g[tid];
        params[1][tid] = b2g[tid];
        params[2][tid] = b3g[tid];
        params[3][tid] = gg[tid];
        params[4][tid] = betag[tid];
    }
    __syncthreads();
    const int wid = tid >> 6, lane = tid & 63;
    const int er = lane & 15, a = lane >> 4;
    const int ebase = (blockIdx.x * 4 + wid) * (16 * ET);
    if (ebase >= E) return;
    u16* ht = htile[wid];
    const int swz = (er & 7) << 4;

    int eidx[ET], cn[ET], sn[ET];
#pragma unroll
    for (int t = 0; t < ET; ++t) {
        int e = ebase + t * 16 + er;
        if (e > E - 1) e = E - 1;
        eidx[t] = e;
        int2 ii = *(const int2*)(edge_idx + 2 * e);
        cn[t] = ii.x; sn[t] = ii.y;
    }

    f32x4 acc[ET][4];
#pragma unroll
    for (int t = 0; t < ET; ++t)
#pragma unroll
        for (int m = 0; m < 4; ++m) acc[t][m] = 0.0f;

    // ---- layer 1: K = 192, 6 phases; A-frags loaded once per phase, reused x ET
#pragma unroll
    for (int s = 0; s < 6; ++s) {
        bf16x8 af[4];
#pragma unroll
        for (int m = 0; m < 4; ++m)
            af[m] = *(const bf16x8*)(Pw + PK_EW1 + ((s * 4 + m) * 64 + lane) * 8);
        bf16x8 bf[ET];
#pragma unroll
        for (int t = 0; t < ET; ++t) {
            const float* src;
            if (s < 2)      src = edge_feat + (size_t)eidx[t] * 64 + s * 32 + a * 8;
            else if (s < 4) src = node_feat + (size_t)cn[t] * 64 + (s - 2) * 32 + a * 8;
            else            src = node_feat + (size_t)sn[t] * 64 + (s - 4) * 32 + a * 8;
            bf[t] = load8f_bf(src);
        }
#pragma unroll
        for (int t = 0; t < ET; ++t)
#pragma unroll
            for (int m = 0; m < 4; ++m)
                acc[t][m] = __builtin_amdgcn_mfma_f32_16x16x32_bf16(af[m], bf[t], acc[t][m], 0, 0, 0);
    }

    // ---- layers 2 & 3 per subtile, reusing the single wave-private tile
#pragma unroll
    for (int t = 0; t < ET; ++t) {
        // bias + relu (layer1) -> tile
#pragma unroll
        for (int m = 0; m < 4; ++m) {
            float v0 = fmaxf(acc[t][m][0] + params[0][16 * m + 4 * a + 0], 0.0f);
            float v1 = fmaxf(acc[t][m][1] + params[0][16 * m + 4 * a + 1], 0.0f);
            float v2 = fmaxf(acc[t][m][2] + params[0][16 * m + 4 * a + 2], 0.0f);
            float v3 = fmaxf(acc[t][m][3] + params[0][16 * m + 4 * a + 3], 0.0f);
            u32x2 pv; pv[0] = pk2(v0, v1); pv[1] = pk2(v2, v3);
            int boff = (er * 128 + (16 * m + 4 * a) * 2) ^ swz;
            *(u32x2*)((char*)ht + boff) = pv;
        }
        // layer 2: K = 64
        f32x4 a2[4];
#pragma unroll
        for (int m = 0; m < 4; ++m) a2[m] = 0.0f;
#pragma unroll
        for (int s = 0; s < 2; ++s) {
            bf16x8 af[4];
#pragma unroll
            for (int m = 0; m < 4; ++m)
                af[m] = *(const bf16x8*)(Pw + PK_EW2 + ((s * 4 + m) * 64 + lane) * 8);
            int boff = (er * 128 + s * 64 + a * 16) ^ swz;
            bf16x8 bf = *(const bf16x8*)((char*)ht + boff);
#pragma unroll
            for (int m = 0; m < 4; ++m)
                a2[m] = __builtin_amdgcn_mfma_f32_16x16x32_bf16(af[m], bf, a2[m], 0, 0, 0);
        }
        // bias + relu (layer2) -> tile (overwrite; same-wave DS ops are in-order)
#pragma unroll
        for (int m = 0; m < 4; ++m) {
            float v0 = fmaxf(a2[m][0] + params[1][16 * m + 4 * a + 0], 0.0f);
            float v1 = fmaxf(a2[m][1] + params[1][16 * m + 4 * a + 1], 0.0f);
            float v2 = fmaxf(a2[m][2] + params[1][16 * m + 4 * a + 2], 0.0f);
            float v3 = fmaxf(a2[m][3] + params[1][16 * m + 4 * a + 3], 0.0f);
            u32x2 pv; pv[0] = pk2(v0, v1); pv[1] = pk2(v2, v3);
            int boff = (er * 128 + (16 * m + 4 * a) * 2) ^ swz;
            *(u32x2*)((char*)ht + boff) = pv;
        }
        // layer 3: K = 64 (no relu)
        f32x4 a3[4];
#pragma unroll
        for (int m = 0; m < 4; ++m) a3[m] = 0.0f;
#pragma unroll
        for (int s = 0; s < 2; ++s) {
            bf16x8 af[4];
#pragma unroll
            for (int m = 0; m < 4; ++m)
                af[m] = *(const bf16x8*)(Pw + PK_EW3 + ((s * 4 + m) * 64 + lane) * 8);
            int boff = (er * 128 + s * 64 + a * 16) ^ swz;
            bf16x8 bf = *(const bf16x8*)((char*)ht + boff);
#pragma unroll
            for (int m = 0; m < 4; ++m)
                a3[m] = __builtin_amdgcn_mfma_f32_16x16x32_bf16(af[m], bf, a3[m], 0, 0, 0);
        }
        // LayerNorm + store
        float vals[16], sum = 0.0f, ssq = 0.0f;
#pragma unroll
        for (int m = 0; m < 4; ++m)
#pragma unroll
            for (int r = 0; r < 4; ++r) {
                float v = a3[m][r] + params[2][16 * m + 4 * a + r];
                vals[4 * m + r] = v; sum += v; ssq += v * v;
            }
        sum += __shfl_xor(sum, 16, 64); sum += __shfl_xor(sum, 32, 64);
        ssq += __shfl_xor(ssq, 16, 64); ssq += __shfl_xor(ssq, 32, 64);
        const float mean = sum * 0.015625f;
        const float var = ssq * 0.015625f - mean * mean;
        const float inv = rsqrtf(var + 1e-5f);
        const int e = ebase + t * 16 + er;
        if (e < E) {
#pragma unroll
            for (int m = 0; m < 4; ++m) {
                f32x4 o;
#pragma unroll
                for (int r = 0; r < 4; ++r) {
                    int f = 16 * m + 4 * a + r;
                    o[r] = (vals[4 * m + r] - mean) * inv * params[3][f] + params[4][f];
                }
                *(f32x4*)(out_edge + (size_t)e * 64 + 16 * m + 4 * a) = o;
            }
        }
    }
}

// ---------------- node MLP + LN (register segment-sum gather, unrolled x8) ----------------
__global__ __launch_bounds__(256) void node_mlp_kernel(
    const float* __restrict__ node_feat, const float* __restrict__ proc_edge,
    const int* __restrict__ off, const int* __restrict__ csr,
    const u16* __restrict__ Pw,
    const float* __restrict__ b1g, const float* __restrict__ b2g, const float* __restrict__ b3g,
    const float* __restrict__ gg, const float* __restrict__ betag,
    float* __restrict__ out_node, int N)
{
    __shared__ float params[5][64];
    __shared__ u16 htile[4][1024];
    const int tid = threadIdx.x;
    if (tid < 64) {
        params[0][tid] = b1g[tid];
        params[1][tid] = b2g[tid];
        params[2][tid] = b3g[tid];
        params[3][tid] = gg[tid];
        params[4][tid] = betag[tid];
    }
    __syncthreads();
    const int wid = tid >> 6, lane = tid & 63;
    const int er = lane & 15, a = lane >> 4;
    const int nbase = (blockIdx.x * 4 + wid) * 16;
    if (nbase >= N) return;
    const int n = nbase + er;
    u16* ht = htile[wid];
    const int swz = (er & 7) << 4;

    // ---- segment-sum gather, unrolled x8 for memory-level parallelism
    f32x4 g0a = 0.0f, g0b = 0.0f, g1a = 0.0f, g1b = 0.0f;
    {
        const int beg = off[n], end = off[n + 1];
        int j = beg;
        for (; j + 7 < end; j += 8) {
#pragma unroll
            for (int u = 0; u < 8; ++u) {
                const float* row = proc_edge + (size_t)csr[j + u] * 64;
                g0a += *(const f32x4*)(row + a * 8);
                g0b += *(const f32x4*)(row + a * 8 + 4);
                g1a += *(const f32x4*)(row + 32 + a * 8);
                g1b += *(const f32x4*)(row + 32 + a * 8 + 4);
            }
        }
        for (; j < end; ++j) {
            const float* row = proc_edge + (size_t)csr[j] * 64;
            g0a += *(const f32x4*)(row + a * 8);
            g0b += *(const f32x4*)(row + a * 8 + 4);
            g1a += *(const f32x4*)(row + 32 + a * 8);
            g1b += *(const f32x4*)(row + 32 + a * 8 + 4);
        }
    }

    f32x4 acc[4];
#pragma unroll
    for (int m = 0; m < 4; ++m) acc[m] = 0.0f;

    // ---- layer 1: K = 128
#pragma unroll
    for (int s = 0; s < 4; ++s) {
        bf16x8 af[4];
#pragma unroll
        for (int m = 0; m < 4; ++m)
            af[m] = *(const bf16x8*)(Pw + PK_NW1 + ((s * 4 + m) * 64 + lane) * 8);
        bf16x8 bf;
        if (s < 2)       bf = load8f_bf(node_feat + (size_t)n * 64 + s * 32 + a * 8);
        else if (s == 2) bf = cvt2bf(g0a, g0b);
        else             bf = cvt2bf(g1a, g1b);
#pragma unroll
        for (int m = 0; m < 4; ++m)
            acc[m] = __builtin_amdgcn_mfma_f32_16x16x32_bf16(af[m], bf, acc[m], 0, 0, 0);
    }
#pragma unroll
    for (int m = 0; m < 4; ++m) {
        float v0 = fmaxf(acc[m][0] + params[0][16 * m + 4 * a + 0], 0.0f);
        float v1 = fmaxf(acc[m][1] + params[0][16 * m + 4 * a + 1], 0.0f);
        float v2 = fmaxf(acc[m][2] + params[0][16 * m + 4 * a + 2], 0.0f);
        float v3 = fmaxf(acc[m][3] + params[0][16 * m + 4 * a + 3], 0.0f);
        u32x2 pv; pv[0] = pk2(v0, v1); pv[1] = pk2(v2, v3);
        int boff = (er * 128 + (16 * m + 4 * a) * 2) ^ swz;
        *(u32x2*)((char*)ht + boff) = pv;
    }

    // ---- layer 2
#pragma unroll
    for (int m = 0; m < 4; ++m) acc[m] = 0.0f;
#pragma unroll
    for (int s = 0; s < 2; ++s) {
        bf16x8 af[4];
#pragma unroll
        for (int m = 0; m < 4; ++m)
            af[m] = *(const bf16x8*)(Pw + PK_NW2 + ((s * 4 + m) * 64 + lane) * 8);
        int boff = (er * 128 + s * 64 + a * 16) ^ swz;
        bf16x8 bf = *(const bf16x8*)((char*)ht + boff);
#pragma unroll
        for (int m = 0; m < 4; ++m)
            acc[m] = __builtin_amdgcn_mfma_f32_16x16x32_bf16(af[m], bf, acc[m], 0, 0, 0);
    }
#pragma unroll
    for (int m = 0; m < 4; ++m) {
        float v0 = fmaxf(acc[m][0] + params[1][16 * m + 4 * a + 0], 0.0f);
        float v1 = fmaxf(acc[m][1] + params[1][16 * m + 4 * a + 1], 0.0f);
        float v2 = fmaxf(acc[m][2] + params[1][16 * m + 4 * a + 2], 0.0f);
        float v3 = fmaxf(acc[m][3] + params[1][16 * m + 4 * a + 3], 0.0f);
        u32x2 pv; pv[0] = pk2(v0, v1); pv[1] = pk2(v2, v3);
        int boff = (er * 128 + (16 * m + 4 * a) * 2) ^ swz;
        *(u32x2*)((char*)ht + boff) = pv;
    }

    // ---- layer 3 + LN
#pragma unroll
    for (int m = 0; m < 4; ++m) acc[m] = 0.0f;
#pragma unroll
    for (int s = 0; s < 2; ++s) {
        bf16x8 af[4];
#pragma unroll
        for (int m = 0; m < 4; ++m)
            af[m] = *(const bf16x8*)(Pw + PK_NW3 + ((s * 4 + m) * 64 + lane) * 8);
        int boff = (er * 128 + s * 64 + a * 16) ^ swz;
        bf16x8 bf = *(const bf16x8*)((char*)ht + boff);
#pragma unroll
        for (int m = 0; m < 4; ++m)
            acc[m] = __builtin_amdgcn_mfma_f32_16x16x32_bf16(af[m], bf, acc[m], 0, 0, 0);
    }
    float vals[16], sum = 0.0f, ssq = 0.0f;
#pragma unroll
    for (int m = 0; m < 4; ++m)
#pragma unroll
        for (int r = 0; r < 4; ++r) {
            float v = acc[m][r] + params[2][16 * m + 4 * a + r];
            vals[4 * m + r] = v; sum += v; ssq += v * v;
        }
    sum += __shfl_xor(sum, 16, 64); sum += __shfl_xor(sum, 32, 64);
    ssq += __shfl_xor(ssq, 16, 64); ssq += __shfl_xor(ssq, 32, 64);
    const float mean = sum * 0.015625f;
    const float var = ssq * 0.015625f - mean * mean;
    const float inv = rsqrtf(var + 1e-5f);
#pragma unroll
    for (int m = 0; m < 4; ++m) {
        f32x4 o;
#pragma unroll
        for (int r = 0; r < 4; ++r) {
            int f = 16 * m + 4 * a + r;
            o[r] = (vals[4 * m + r] - mean) * inv * params[3][f] + params[4][f];
        }
        *(f32x4*)(out_node + (size_t)n * 64 + 16 * m + 4 * a) = o;
    }
}

extern "C" void kernel_launch(void* const* d_in, const int* in_sizes, int n_in,
                              void* d_out, int out_size, void* d_ws, size_t ws_size,
                              hipStream_t stream) {
    const float* node_feat = (const float*)d_in[0];
    const float* edge_feat = (const float*)d_in[1];
    const int* edge_idx  = (const int*)d_in[2];
    const float* eW1 = (const float*)d_in[4];
    const float* eb1 = (const float*)d_in[5];
    const float* eW2 = (const float*)d_in[6];
    const float* eb2 = (const float*)d_in[7];
    const float* eW3 = (const float*)d_in[8];
    const float* eb3 = (const float*)d_in[9];
    const float* eg  = (const float*)d_in[10];
    const float* ebt = (const float*)d_in[11];
    const float* nW1 = (const float*)d_in[12];
    const float* nb1 = (const float*)d_in[13];
    const float* nW2 = (const float*)d_in[14];
    const float* nb2 = (const float*)d_in[15];
    const float* nW3 = (const float*)d_in[16];
    const float* nb3 = (const float*)d_in[17];
    const float* ng  = (const float*)d_in[18];
    const float* nbt = (const float*)d_in[19];

    const int N = in_sizes[0] / 64;
    const int E = in_sizes[1] / 64;
    const int nparts = (N + 255) / 256;

    // ws layout
    char* w = (char*)d_ws;
    int* off      = (int*)w;                    w += (size_t)(N + 1) * 4;
    int* pos      = (int*)w;                    w += (size_t)N * 4;
    int* partials = (int*)w;                    w += 256 * 4;
    int* csr      = (int*)w;                    w += (size_t)E * 4;
    u16* Pw       = (u16*)w;

    float* out_edge = (float*)d_out;
    float* out_node = out_edge + (size_t)E * 64;

    pack_weights_kernel<<<(PK_TOTAL + 255) / 256, 256, 0, stream>>>(eW1, eW2, eW3, nW1, nW2, nW3, Pw);

    // big streaming kernel first
    const int eblocks = (E + (64 * ET) - 1) / (64 * ET);
    edge_mlp_kernel<<<eblocks, 256, 0, stream>>>(node_feat, edge_feat, edge_idx, Pw,
                                                 eb1, eb2, eb3, eg, ebt, out_edge, E);

    // CSR build (pos doubles as degree histogram)
    hipMemsetAsync(pos, 0, (size_t)N * 4, stream);
    degree_kernel<<<(E + 255) / 256, 256, 0, stream>>>(edge_idx, pos, E);
    scan_blocks_kernel<<<nparts, 256, 0, stream>>>(pos, off, partials, N);
    scan_partials_kernel<<<1, 256, 0, stream>>>(partials, nparts);
    finalize_offsets_kernel<<<(N + 255) / 256, 256, 0, stream>>>(off, pos, partials, N, E);
    fill_csr_kernel<<<(E + 255) / 256, 256, 0, stream>>>(edge_idx, pos, csr, E);

    const int nblocks = (N + 63) / 64;
    node_mlp_kernel<<<nblocks, 256, 0, stream>>>(node_feat, out_edge, off, csr, Pw,
                                                 nb1, nb2, nb3, ng, nbt, out_node, N);
}

// Round 6
// 580.257 us; speedup vs baseline: 1.1168x; 1.1168x over previous
//
#include <hip/hip_runtime.h>

typedef unsigned short u16;
typedef unsigned int u32;
typedef __attribute__((ext_vector_type(8))) __bf16 bf16x8;
typedef __attribute__((ext_vector_type(4))) float f32x4;
typedef __attribute__((ext_vector_type(2))) u32 u32x2;
typedef __attribute__((ext_vector_type(4))) u32 u32x4;

__device__ __forceinline__ u16 f2bf(float f) {
    u32 u = __float_as_uint(f);
    u = (u + 0x7FFFu + ((u >> 16) & 1u)) >> 16;
    return (u16)u;
}
__device__ __forceinline__ bf16x8 cvt2bf(f32x4 lo, f32x4 hi) {
    bf16x8 r;
    r[0] = (__bf16)lo[0]; r[1] = (__bf16)lo[1]; r[2] = (__bf16)lo[2]; r[3] = (__bf16)lo[3];
    r[4] = (__bf16)hi[0]; r[5] = (__bf16)hi[1]; r[6] = (__bf16)hi[2]; r[7] = (__bf16)hi[3];
    return r;
}
__device__ __forceinline__ bf16x8 load8f_bf(const float* p) {
    return cvt2bf(*(const f32x4*)p, *(const f32x4*)(p + 4));
}
__device__ __forceinline__ u32 pk2(float x, float y) {
    __bf16 bx = (__bf16)x, by = (__bf16)y;
    return (u32)__builtin_bit_cast(u16, bx) | ((u32)__builtin_bit_cast(u16, by) << 16);
}

// packed A-fragment (W^T) layout, per layer: idx = ((s*4 + m)*64 + lane)*8 + j
// value = W[k][16*m + (lane&15)], k = s*32 + (lane>>4)*8 + j
#define PK_EW1 0
#define PK_EW2 12288
#define PK_EW3 16384
#define PK_NW1 20480
#define PK_NW2 28672
#define PK_NW3 32768
#define PK_TOTAL 36864
#define EW_U16 20480   // edge-MLP weight region (u16 count) staged to LDS

__global__ void pack_weights_kernel(const float* __restrict__ eW1, const float* __restrict__ eW2,
                                    const float* __restrict__ eW3, const float* __restrict__ nW1,
                                    const float* __restrict__ nW2, const float* __restrict__ nW3,
                                    u16* __restrict__ P) {
    int idx = blockIdx.x * blockDim.x + threadIdx.x;
    if (idx >= PK_TOTAL) return;
    const float* W; int base;
    if (idx < PK_EW2)      { W = eW1; base = PK_EW1; }
    else if (idx < PK_EW3) { W = eW2; base = PK_EW2; }
    else if (idx < PK_NW1) { W = eW3; base = PK_EW3; }
    else if (idx < PK_NW2) { W = nW1; base = PK_NW1; }
    else if (idx < PK_NW3) { W = nW2; base = PK_NW2; }
    else                   { W = nW3; base = PK_NW3; }
    int r = idx - base;
    int j = r & 7, lane = (r >> 3) & 63, m = (r >> 9) & 3, s = r >> 11;
    int k = s * 32 + (lane >> 4) * 8 + j;
    int col = 16 * m + (lane & 15);
    P[idx] = f2bf(W[k * 64 + col]);
}

// ---------------- CSR build ----------------
__global__ void degree_kernel(const int* __restrict__ edge_idx, int* __restrict__ deg, int E) {
    int e = blockIdx.x * blockDim.x + threadIdx.x;
    if (e < E) atomicAdd(&deg[edge_idx[2 * e]], 1);
}

__global__ void scan_blocks_kernel(const int* __restrict__ deg, int* __restrict__ off,
                                   int* __restrict__ partials, int N) {
    __shared__ int sh[256];
    const int t = threadIdx.x;
    const int g = blockIdx.x * 256 + t;
    int v = (g < N) ? deg[g] : 0;
    sh[t] = v;
    __syncthreads();
#pragma unroll
    for (int d = 1; d < 256; d <<= 1) {
        int add = (t >= d) ? sh[t - d] : 0;
        __syncthreads();
        sh[t] += add;
        __syncthreads();
    }
    if (g < N) off[g] = sh[t] - v;
    if (t == 255) partials[blockIdx.x] = sh[255];
}

__global__ void scan_partials_kernel(int* __restrict__ partials, int nparts) {
    __shared__ int sh[256];
    const int t = threadIdx.x;
    int v = (t < nparts) ? partials[t] : 0;
    sh[t] = v;
    __syncthreads();
#pragma unroll
    for (int d = 1; d < 256; d <<= 1) {
        int add = (t >= d) ? sh[t - d] : 0;
        __syncthreads();
        sh[t] += add;
        __syncthreads();
    }
    if (t < nparts) partials[t] = sh[t] - v;
}

__global__ void finalize_offsets_kernel(int* __restrict__ off, int* __restrict__ pos,
                                        const int* __restrict__ partials, int N, int E) {
    int g = blockIdx.x * blockDim.x + threadIdx.x;
    if (g < N) {
        int o = off[g] + partials[g >> 8];
        off[g] = o;
        pos[g] = o;
    }
    if (g == 0) off[N] = E;
}

__global__ void fill_csr_kernel(const int* __restrict__ edge_idx, int* __restrict__ pos,
                                int* __restrict__ csr, int E) {
    int e = blockIdx.x * blockDim.x + threadIdx.x;
    if (e < E) {
        int slot = atomicAdd(&pos[edge_idx[2 * e]], 1);
        csr[slot] = e;
    }
}

// ---------------- segment-sum gather: one wave per node, bf16 output ----------------
__global__ __launch_bounds__(256) void gather_kernel(
    const float* __restrict__ proc_edge, const int* __restrict__ off,
    const int* __restrict__ csr, u16* __restrict__ nodal16, int N)
{
    const int wid = threadIdx.x >> 6, lane = threadIdx.x & 63;
    const int n = blockIdx.x * 4 + wid;
    if (n >= N) return;
    const int r = lane >> 4;      // row slot 0..3
    const int q = lane & 15;      // 4-float chunk within the 64-dim row
    const int beg = off[n], end = off[n + 1];
    f32x4 v0 = 0.0f, v1 = 0.0f;
    int j = beg + r;
    for (; j + 4 < end; j += 8) {
        int e0 = csr[j], e1 = csr[j + 4];
        v0 += *(const f32x4*)(proc_edge + (size_t)e0 * 64 + q * 4);
        v1 += *(const f32x4*)(proc_edge + (size_t)e1 * 64 + q * 4);
    }
    if (j < end) {
        int e0 = csr[j];
        v0 += *(const f32x4*)(proc_edge + (size_t)e0 * 64 + q * 4);
    }
    v0 += v1;
#pragma unroll
    for (int i = 0; i < 4; ++i) {
        v0[i] += __shfl_xor(v0[i], 16, 64);
        v0[i] += __shfl_xor(v0[i], 32, 64);
    }
    if (r == 0) {
        u32x2 pv; pv[0] = pk2(v0[0], v0[1]); pv[1] = pk2(v0[2], v0[3]);
        *(u32x2*)(nodal16 + (size_t)n * 64 + q * 4) = pv;
    }
}

// ---------------- edge MLP + LN: weights staged in LDS, batched B-loads ----------------
#define ET 2
__global__ __launch_bounds__(256) void edge_mlp_kernel(
    const float* __restrict__ node_feat, const float* __restrict__ edge_feat,
    const int* __restrict__ edge_idx, const u16* __restrict__ Pw,
    const float* __restrict__ b1g, const float* __restrict__ b2g, const float* __restrict__ b3g,
    const float* __restrict__ gg, const float* __restrict__ betag,
    float* __restrict__ out_edge, int E)
{
    __shared__ u16 wlds[EW_U16];        // 40 KB: all edge-MLP weight fragments
    __shared__ u16 htile[4][1024];      // per-wave 16x64 bf16 tile, XOR-swizzled
    __shared__ float params[5][64];
    const int tid = threadIdx.x;
    // ---- stage all edge weights to LDS (256 threads x 16B x 10 iters = 40960B)
#pragma unroll
    for (int i = 0; i < 10; ++i) {
        u32x4 v = *(const u32x4*)(Pw + (size_t)(i * 256 + tid) * 8);
        *(u32x4*)(wlds + (size_t)(i * 256 + tid) * 8) = v;
    }
    if (tid < 64) {
        params[0][tid] = b1g[tid];
        params[1][tid] = b2g[tid];
        params[2][tid] = b3g[tid];
        params[3][tid] = gg[tid];
        params[4][tid] = betag[tid];
    }
    __syncthreads();

    const int wid = tid >> 6, lane = tid & 63;
    const int er = lane & 15, a = lane >> 4;
    const int ebase = (blockIdx.x * 4 + wid) * (16 * ET);
    if (ebase >= E) return;
    u16* ht = htile[wid];
    const int swz = (er & 7) << 4;

    int eidx[ET], cn[ET], sn[ET];
#pragma unroll
    for (int t = 0; t < ET; ++t) {
        int e = ebase + t * 16 + er;
        if (e > E - 1) e = E - 1;
        eidx[t] = e;
        int2 ii = *(const int2*)(edge_idx + 2 * e);
        cn[t] = ii.x; sn[t] = ii.y;
    }

    f32x4 acc[ET][4];
#pragma unroll
    for (int t = 0; t < ET; ++t)
#pragma unroll
        for (int m = 0; m < 4; ++m) acc[t][m] = 0.0f;

    // ---- layer 1: K = 192; all 12 B-loads of a subtile issued before use
#pragma unroll
    for (int t = 0; t < ET; ++t) {
        f32x4 raw[12];
#pragma unroll
        for (int s = 0; s < 6; ++s) {
            const float* src;
            if (s < 2)      src = edge_feat + (size_t)eidx[t] * 64 + s * 32 + a * 8;
            else if (s < 4) src = node_feat + (size_t)cn[t] * 64 + (s - 2) * 32 + a * 8;
            else            src = node_feat + (size_t)sn[t] * 64 + (s - 4) * 32 + a * 8;
            raw[2 * s]     = *(const f32x4*)src;
            raw[2 * s + 1] = *(const f32x4*)(src + 4);
        }
#pragma unroll
        for (int s = 0; s < 6; ++s) {
            bf16x8 bf = cvt2bf(raw[2 * s], raw[2 * s + 1]);
#pragma unroll
            for (int m = 0; m < 4; ++m) {
                bf16x8 af = *(const bf16x8*)(wlds + PK_EW1 + ((s * 4 + m) * 64 + lane) * 8);
                acc[t][m] = __builtin_amdgcn_mfma_f32_16x16x32_bf16(af, bf, acc[t][m], 0, 0, 0);
            }
        }
    }

    // ---- layers 2 & 3 per subtile (weights from LDS)
#pragma unroll
    for (int t = 0; t < ET; ++t) {
        // bias + relu (layer1) -> tile
#pragma unroll
        for (int m = 0; m < 4; ++m) {
            float v0 = fmaxf(acc[t][m][0] + params[0][16 * m + 4 * a + 0], 0.0f);
            float v1 = fmaxf(acc[t][m][1] + params[0][16 * m + 4 * a + 1], 0.0f);
            float v2 = fmaxf(acc[t][m][2] + params[0][16 * m + 4 * a + 2], 0.0f);
            float v3 = fmaxf(acc[t][m][3] + params[0][16 * m + 4 * a + 3], 0.0f);
            u32x2 pv; pv[0] = pk2(v0, v1); pv[1] = pk2(v2, v3);
            int boff = (er * 128 + (16 * m + 4 * a) * 2) ^ swz;
            *(u32x2*)((char*)ht + boff) = pv;
        }
        // layer 2: K = 64
        f32x4 a2[4];
#pragma unroll
        for (int m = 0; m < 4; ++m) a2[m] = 0.0f;
#pragma unroll
        for (int s = 0; s < 2; ++s) {
            int boff = (er * 128 + s * 64 + a * 16) ^ swz;
            bf16x8 bf = *(const bf16x8*)((char*)ht + boff);
#pragma unroll
            for (int m = 0; m < 4; ++m) {
                bf16x8 af = *(const bf16x8*)(wlds + PK_EW2 + ((s * 4 + m) * 64 + lane) * 8);
                a2[m] = __builtin_amdgcn_mfma_f32_16x16x32_bf16(af, bf, a2[m], 0, 0, 0);
            }
        }
        // bias + relu (layer2) -> tile (same-wave DS ops are in-order)
#pragma unroll
        for (int m = 0; m < 4; ++m) {
            float v0 = fmaxf(a2[m][0] + params[1][16 * m + 4 * a + 0], 0.0f);
            float v1 = fmaxf(a2[m][1] + params[1][16 * m + 4 * a + 1], 0.0f);
            float v2 = fmaxf(a2[m][2] + params[1][16 * m + 4 * a + 2], 0.0f);
            float v3 = fmaxf(a2[m][3] + params[1][16 * m + 4 * a + 3], 0.0f);
            u32x2 pv; pv[0] = pk2(v0, v1); pv[1] = pk2(v2, v3);
            int boff = (er * 128 + (16 * m + 4 * a) * 2) ^ swz;
            *(u32x2*)((char*)ht + boff) = pv;
        }
        // layer 3: K = 64 (no relu)
        f32x4 a3[4];
#pragma unroll
        for (int m = 0; m < 4; ++m) a3[m] = 0.0f;
#pragma unroll
        for (int s = 0; s < 2; ++s) {
            int boff = (er * 128 + s * 64 + a * 16) ^ swz;
            bf16x8 bf = *(const bf16x8*)((char*)ht + boff);
#pragma unroll
            for (int m = 0; m < 4; ++m) {
                bf16x8 af = *(const bf16x8*)(wlds + PK_EW3 + ((s * 4 + m) * 64 + lane) * 8);
                a3[m] = __builtin_amdgcn_mfma_f32_16x16x32_bf16(af, bf, a3[m], 0, 0, 0);
            }
        }
        // LayerNorm + store
        float vals[16], sum = 0.0f, ssq = 0.0f;
#pragma unroll
        for (int m = 0; m < 4; ++m)
#pragma unroll
            for (int r = 0; r < 4; ++r) {
                float v = a3[m][r] + params[2][16 * m + 4 * a + r];
                vals[4 * m + r] = v; sum += v; ssq += v * v;
            }
        sum += __shfl_xor(sum, 16, 64); sum += __shfl_xor(sum, 32, 64);
        ssq += __shfl_xor(ssq, 16, 64); ssq += __shfl_xor(ssq, 32, 64);
        const float mean = sum * 0.015625f;
        const float var = ssq * 0.015625f - mean * mean;
        const float inv = rsqrtf(var + 1e-5f);
        const int e = ebase + t * 16 + er;
        if (e < E) {
#pragma unroll
            for (int m = 0; m < 4; ++m) {
                f32x4 o;
#pragma unroll
                for (int r = 0; r < 4; ++r) {
                    int f = 16 * m + 4 * a + r;
                    o[r] = (vals[4 * m + r] - mean) * inv * params[3][f] + params[4][f];
                }
                *(f32x4*)(out_edge + (size_t)e * 64 + 16 * m + 4 * a) = o;
            }
        }
    }
}

// ---------------- node MLP + LN (nodal precomputed as bf16; linear reads) ----------------
__global__ __launch_bounds__(256) void node_mlp_kernel(
    const float* __restrict__ node_feat, const u16* __restrict__ nodal16,
    const u16* __restrict__ Pw,
    const float* __restrict__ b1g, const float* __restrict__ b2g, const float* __restrict__ b3g,
    const float* __restrict__ gg, const float* __restrict__ betag,
    float* __restrict__ out_node, int N)
{
    __shared__ float params[5][64];
    __shared__ u16 htile[4][1024];
    const int tid = threadIdx.x;
    if (tid < 64) {
        params[0][tid] = b1g[tid];
        params[1][tid] = b2g[tid];
        params[2][tid] = b3g[tid];
        params[3][tid] = gg[tid];
        params[4][tid] = betag[tid];
    }
    __syncthreads();
    const int wid = tid >> 6, lane = tid & 63;
    const int er = lane & 15, a = lane >> 4;
    const int nbase = (blockIdx.x * 4 + wid) * 16;
    if (nbase >= N) return;
    const int n = nbase + er;
    u16* ht = htile[wid];
    const int swz = (er & 7) << 4;

    f32x4 acc[4];
#pragma unroll
    for (int m = 0; m < 4; ++m) acc[m] = 0.0f;

    // ---- layer 1: K = 128 (concat: node_feat | nodal_edge_feat[bf16])
#pragma unroll
    for (int s = 0; s < 4; ++s) {
        bf16x8 af[4];
#pragma unroll
        for (int m = 0; m < 4; ++m)
            af[m] = *(const bf16x8*)(Pw + PK_NW1 + ((s * 4 + m) * 64 + lane) * 8);
        bf16x8 bf;
        if (s < 2) bf = load8f_bf(node_feat + (size_t)n * 64 + s * 32 + a * 8);
        else       bf = *(const bf16x8*)(nodal16 + (size_t)n * 64 + (s - 2) * 32 + a * 8);
#pragma unroll
        for (int m = 0; m < 4; ++m)
            acc[m] = __builtin_amdgcn_mfma_f32_16x16x32_bf16(af[m], bf, acc[m], 0, 0, 0);
    }
#pragma unroll
    for (int m = 0; m < 4; ++m) {
        float v0 = fmaxf(acc[m][0] + params[0][16 * m + 4 * a + 0], 0.0f);
        float v1 = fmaxf(acc[m][1] + params[0][16 * m + 4 * a + 1], 0.0f);
        float v2 = fmaxf(acc[m][2] + params[0][16 * m + 4 * a + 2], 0.0f);
        float v3 = fmaxf(acc[m][3] + params[0][16 * m + 4 * a + 3], 0.0f);
        u32x2 pv; pv[0] = pk2(v0, v1); pv[1] = pk2(v2, v3);
        int boff = (er * 128 + (16 * m + 4 * a) * 2) ^ swz;
        *(u32x2*)((char*)ht + boff) = pv;
    }

    // ---- layer 2
#pragma unroll
    for (int m = 0; m < 4; ++m) acc[m] = 0.0f;
#pragma unroll
    for (int s = 0; s < 2; ++s) {
        bf16x8 af[4];
#pragma unroll
        for (int m = 0; m < 4; ++m)
            af[m] = *(const bf16x8*)(Pw + PK_NW2 + ((s * 4 + m) * 64 + lane) * 8);
        int boff = (er * 128 + s * 64 + a * 16) ^ swz;
        bf16x8 bf = *(const bf16x8*)((char*)ht + boff);
#pragma unroll
        for (int m = 0; m < 4; ++m)
            acc[m] = __builtin_amdgcn_mfma_f32_16x16x32_bf16(af[m], bf, acc[m], 0, 0, 0);
    }
#pragma unroll
    for (int m = 0; m < 4; ++m) {
        float v0 = fmaxf(acc[m][0] + params[1][16 * m + 4 * a + 0], 0.0f);
        float v1 = fmaxf(acc[m][1] + params[1][16 * m + 4 * a + 1], 0.0f);
        float v2 = fmaxf(acc[m][2] + params[1][16 * m + 4 * a + 2], 0.0f);
        float v3 = fmaxf(acc[m][3] + params[1][16 * m + 4 * a + 3], 0.0f);
        u32x2 pv; pv[0] = pk2(v0, v1); pv[1] = pk2(v2, v3);
        int boff = (er * 128 + (16 * m + 4 * a) * 2) ^ swz;
        *(u32x2*)((char*)ht + boff) = pv;
    }

    // ---- layer 3 + LN
#pragma unroll
    for (int m = 0; m < 4; ++m) acc[m] = 0.0f;
#pragma unroll
    for (int s = 0; s < 2; ++s) {
        bf16x8 af[4];
#pragma unroll
        for (int m = 0; m < 4; ++m)
            af[m] = *(const bf16x8*)(Pw + PK_NW3 + ((s * 4 + m) * 64 + lane) * 8);
        int boff = (er * 128 + s * 64 + a * 16) ^ swz;
        bf16x8 bf = *(const bf16x8*)((char*)ht + boff);
#pragma unroll
        for (int m = 0; m < 4; ++m)
            acc[m] = __builtin_amdgcn_mfma_f32_16x16x32_bf16(af[m], bf, acc[m], 0, 0, 0);
    }
    float vals[16], sum = 0.0f, ssq = 0.0f;
#pragma unroll
    for (int m = 0; m < 4; ++m)
#pragma unroll
        for (int r = 0; r < 4; ++r) {
            float v = acc[m][r] + params[2][16 * m + 4 * a + r];
            vals[4 * m + r] = v; sum += v; ssq += v * v;
        }
    sum += __shfl_xor(sum, 16, 64); sum += __shfl_xor(sum, 32, 64);
    ssq += __shfl_xor(ssq, 16, 64); ssq += __shfl_xor(ssq, 32, 64);
    const float mean = sum * 0.015625f;
    const float var = ssq * 0.015625f - mean * mean;
    const float inv = rsqrtf(var + 1e-5f);
#pragma unroll
    for (int m = 0; m < 4; ++m) {
        f32x4 o;
#pragma unroll
        for (int r = 0; r < 4; ++r) {
            int f = 16 * m + 4 * a + r;
            o[r] = (vals[4 * m + r] - mean) * inv * params[3][f] + params[4][f];
        }
        *(f32x4*)(out_node + (size_t)n * 64 + 16 * m + 4 * a) = o;
    }
}

extern "C" void kernel_launch(void* const* d_in, const int* in_sizes, int n_in,
                              void* d_out, int out_size, void* d_ws, size_t ws_size,
                              hipStream_t stream) {
    const float* node_feat = (const float*)d_in[0];
    const float* edge_feat = (const float*)d_in[1];
    const int* edge_idx  = (const int*)d_in[2];
    const float* eW1 = (const float*)d_in[4];
    const float* eb1 = (const float*)d_in[5];
    const float* eW2 = (const float*)d_in[6];
    const float* eb2 = (const float*)d_in[7];
    const float* eW3 = (const float*)d_in[8];
    const float* eb3 = (const float*)d_in[9];
    const float* eg  = (const float*)d_in[10];
    const float* ebt = (const float*)d_in[11];
    const float* nW1 = (const float*)d_in[12];
    const float* nb1 = (const float*)d_in[13];
    const float* nW2 = (const float*)d_in[14];
    const float* nb2 = (const float*)d_in[15];
    const float* nW3 = (const float*)d_in[16];
    const float* nb3 = (const float*)d_in[17];
    const float* ng  = (const float*)d_in[18];
    const float* nbt = (const float*)d_in[19];

    const int N = in_sizes[0] / 64;
    const int E = in_sizes[1] / 64;
    const int nparts = (N + 255) / 256;

    // ws layout
    char* w = (char*)d_ws;
    int* off      = (int*)w;                    w += (size_t)(N + 1) * 4;
    int* pos      = (int*)w;                    w += (size_t)N * 4;
    int* partials = (int*)w;                    w += 256 * 4;
    int* csr      = (int*)w;                    w += (size_t)E * 4;
    u16* Pw       = (u16*)w;                    w += (size_t)PK_TOTAL * 2;
    u16* nodal16  = (u16*)w;                    // N*64 bf16

    float* out_edge = (float*)d_out;
    float* out_node = out_edge + (size_t)E * 64;

    pack_weights_kernel<<<(PK_TOTAL + 255) / 256, 256, 0, stream>>>(eW1, eW2, eW3, nW1, nW2, nW3, Pw);

    // big streaming kernel first
    const int eblocks = (E + (64 * ET) - 1) / (64 * ET);
    edge_mlp_kernel<<<eblocks, 256, 0, stream>>>(node_feat, edge_feat, edge_idx, Pw,
                                                 eb1, eb2, eb3, eg, ebt, out_edge, E);

    // CSR build (pos doubles as degree histogram)
    hipMemsetAsync(pos, 0, (size_t)N * 4, stream);
    degree_kernel<<<(E + 255) / 256, 256, 0, stream>>>(edge_idx, pos, E);
    scan_blocks_kernel<<<nparts, 256, 0, stream>>>(pos, off, partials, N);
    scan_partials_kernel<<<1, 256, 0, stream>>>(partials, nparts);
    finalize_offsets_kernel<<<(N + 255) / 256, 256, 0, stream>>>(off, pos, partials, N, E);
    fill_csr_kernel<<<(E + 255) / 256, 256, 0, stream>>>(edge_idx, pos, csr, E);

    // wide segment-sum gather (one wave per node)
    gather_kernel<<<(N + 3) / 4, 256, 0, stream>>>(out_edge, off, csr, nodal16, N);

    const int nblocks = (N + 63) / 64;
    node_mlp_kernel<<<nblocks, 256, 0, stream>>>(node_feat, nodal16, Pw,
                                                 nb1, nb2, nb3, ng, nbt, out_node, N);
}

// Round 7
// 570.636 us; speedup vs baseline: 1.1357x; 1.0169x over previous
//
#include <hip/hip_runtime.h>

typedef unsigned short u16;
typedef unsigned int u32;
typedef __attribute__((ext_vector_type(8))) __bf16 bf16x8;
typedef __attribute__((ext_vector_type(4))) float f32x4;
typedef __attribute__((ext_vector_type(2))) u32 u32x2;
typedef __attribute__((ext_vector_type(4))) u32 u32x4;

__device__ __forceinline__ u16 f2bf(float f) {
    u32 u = __float_as_uint(f);
    u = (u + 0x7FFFu + ((u >> 16) & 1u)) >> 16;
    return (u16)u;
}
__device__ __forceinline__ bf16x8 cvt2bf(f32x4 lo, f32x4 hi) {
    bf16x8 r;
    r[0] = (__bf16)lo[0]; r[1] = (__bf16)lo[1]; r[2] = (__bf16)lo[2]; r[3] = (__bf16)lo[3];
    r[4] = (__bf16)hi[0]; r[5] = (__bf16)hi[1]; r[6] = (__bf16)hi[2]; r[7] = (__bf16)hi[3];
    return r;
}
__device__ __forceinline__ bf16x8 load8f_bf(const float* p) {
    return cvt2bf(*(const f32x4*)p, *(const f32x4*)(p + 4));
}
__device__ __forceinline__ u32 pk2(float x, float y) {
    __bf16 bx = (__bf16)x, by = (__bf16)y;
    return (u32)__builtin_bit_cast(u16, bx) | ((u32)__builtin_bit_cast(u16, by) << 16);
}

// packed A-fragment (W^T) layout, per layer: idx = ((s*4 + m)*64 + lane)*8 + j
// value = W[k][16*m + (lane&15)], k = s*32 + (lane>>4)*8 + j
#define PK_EW1 0
#define PK_EW2 12288
#define PK_EW3 16384
#define PK_NW1 20480
#define PK_NW2 28672
#define PK_NW3 32768
#define PK_TOTAL 36864

__global__ void pack_weights_kernel(const float* __restrict__ eW1, const float* __restrict__ eW2,
                                    const float* __restrict__ eW3, const float* __restrict__ nW1,
                                    const float* __restrict__ nW2, const float* __restrict__ nW3,
                                    u16* __restrict__ P) {
    int idx = blockIdx.x * blockDim.x + threadIdx.x;
    if (idx >= PK_TOTAL) return;
    const float* W; int base;
    if (idx < PK_EW2)      { W = eW1; base = PK_EW1; }
    else if (idx < PK_EW3) { W = eW2; base = PK_EW2; }
    else if (idx < PK_NW1) { W = eW3; base = PK_EW3; }
    else if (idx < PK_NW2) { W = nW1; base = PK_NW1; }
    else if (idx < PK_NW3) { W = nW2; base = PK_NW2; }
    else                   { W = nW3; base = PK_NW3; }
    int r = idx - base;
    int j = r & 7, lane = (r >> 3) & 63, m = (r >> 9) & 3, s = r >> 11;
    int k = s * 32 + (lane >> 4) * 8 + j;
    int col = 16 * m + (lane & 15);
    P[idx] = f2bf(W[k * 64 + col]);
}

// ---------------- CSR build ----------------
__global__ void degree_kernel(const int* __restrict__ edge_idx, int* __restrict__ deg, int E) {
    int e = blockIdx.x * blockDim.x + threadIdx.x;
    if (e < E) atomicAdd(&deg[edge_idx[2 * e]], 1);
}

__global__ void scan_blocks_kernel(const int* __restrict__ deg, int* __restrict__ off,
                                   int* __restrict__ partials, int N) {
    __shared__ int sh[256];
    const int t = threadIdx.x;
    const int g = blockIdx.x * 256 + t;
    int v = (g < N) ? deg[g] : 0;
    sh[t] = v;
    __syncthreads();
#pragma unroll
    for (int d = 1; d < 256; d <<= 1) {
        int add = (t >= d) ? sh[t - d] : 0;
        __syncthreads();
        sh[t] += add;
        __syncthreads();
    }
    if (g < N) off[g] = sh[t] - v;
    if (t == 255) partials[blockIdx.x] = sh[255];
}

__global__ void scan_partials_kernel(int* __restrict__ partials, int nparts) {
    __shared__ int sh[256];
    const int t = threadIdx.x;
    int v = (t < nparts) ? partials[t] : 0;
    sh[t] = v;
    __syncthreads();
#pragma unroll
    for (int d = 1; d < 256; d <<= 1) {
        int add = (t >= d) ? sh[t - d] : 0;
        __syncthreads();
        sh[t] += add;
        __syncthreads();
    }
    if (t < nparts) partials[t] = sh[t] - v;
}

__global__ void finalize_offsets_kernel(int* __restrict__ off, int* __restrict__ pos,
                                        const int* __restrict__ partials, int N, int E) {
    int g = blockIdx.x * blockDim.x + threadIdx.x;
    if (g < N) {
        int o = off[g] + partials[g >> 8];
        off[g] = o;
        pos[g] = o;
    }
    if (g == 0) off[N] = E;
}

__global__ void fill_csr_kernel(const int* __restrict__ edge_idx, int* __restrict__ pos,
                                int* __restrict__ csr, int E) {
    int e = blockIdx.x * blockDim.x + threadIdx.x;
    if (e < E) {
        int slot = atomicAdd(&pos[edge_idx[2 * e]], 1);
        csr[slot] = e;
    }
}

// ---------------- segment-sum gather: one wave per node, 4 streams, bf16 output ----------------
__global__ __launch_bounds__(256) void gather_kernel(
    const float* __restrict__ proc_edge, const int* __restrict__ off,
    const int* __restrict__ csr, u16* __restrict__ nodal16, int N)
{
    const int wid = threadIdx.x >> 6, lane = threadIdx.x & 63;
    const int n = blockIdx.x * 4 + wid;
    if (n >= N) return;
    const int r = lane >> 4;      // row slot 0..3
    const int q = lane & 15;      // 4-float chunk within the 64-dim row
    const int beg = off[n], end = off[n + 1];
    f32x4 v0 = 0.0f, v1 = 0.0f, v2 = 0.0f, v3 = 0.0f;
    int j = beg + r;
    for (; j + 12 < end; j += 16) {
        int e0 = csr[j], e1 = csr[j + 4], e2 = csr[j + 8], e3 = csr[j + 12];
        v0 += *(const f32x4*)(proc_edge + (size_t)e0 * 64 + q * 4);
        v1 += *(const f32x4*)(proc_edge + (size_t)e1 * 64 + q * 4);
        v2 += *(const f32x4*)(proc_edge + (size_t)e2 * 64 + q * 4);
        v3 += *(const f32x4*)(proc_edge + (size_t)e3 * 64 + q * 4);
    }
    for (; j < end; j += 4) {
        int e0 = csr[j];
        v0 += *(const f32x4*)(proc_edge + (size_t)e0 * 64 + q * 4);
    }
    v0 += v1; v2 += v3; v0 += v2;
#pragma unroll
    for (int i = 0; i < 4; ++i) {
        v0[i] += __shfl_xor(v0[i], 16, 64);
        v0[i] += __shfl_xor(v0[i], 32, 64);
    }
    if (r == 0) {
        u32x2 pv; pv[0] = pk2(v0[0], v0[1]); pv[1] = pk2(v0[2], v0[3]);
        *(u32x2*)(nodal16 + (size_t)n * 64 + q * 4) = pv;
    }
}

// ---------------- edge MLP + LN: 512 threads, two-phase weight staging ----------------
#define ET 2
__global__ __launch_bounds__(512, 6) void edge_mlp_kernel(
    const float* __restrict__ node_feat, const float* __restrict__ edge_feat,
    const int* __restrict__ edge_idx, const u16* __restrict__ Pw,
    const float* __restrict__ b1g, const float* __restrict__ b2g, const float* __restrict__ b3g,
    const float* __restrict__ gg, const float* __restrict__ betag,
    float* __restrict__ out_edge, int E)
{
    __shared__ u16 wlds[12288];     // 24 KB: phase A = EW1; phase B = EW2|EW3
    __shared__ u16 htile[8][1024];  // per-wave 16x64 bf16 tile, XOR-swizzled
    __shared__ float params[5][64];
    const int tid = threadIdx.x;
    // ---- stage layer-1 weights (24 KB)
#pragma unroll
    for (int i = 0; i < 3; ++i) {
        int idx = i * 512 + tid;
        *(u32x4*)(wlds + (size_t)idx * 8) = *(const u32x4*)(Pw + PK_EW1 + (size_t)idx * 8);
    }
    if (tid < 64) {
        params[0][tid] = b1g[tid];
        params[1][tid] = b2g[tid];
        params[2][tid] = b3g[tid];
        params[3][tid] = gg[tid];
        params[4][tid] = betag[tid];
    }
    __syncthreads();

    const int wid = tid >> 6, lane = tid & 63;
    const int er = lane & 15, a = lane >> 4;
    const int ebase = (blockIdx.x * 8 + wid) * (16 * ET);
    u16* ht = htile[wid];
    const int swz = (er & 7) << 4;

    int eidx[ET], cn[ET], sn[ET];
#pragma unroll
    for (int t = 0; t < ET; ++t) {
        int e = ebase + t * 16 + er;
        if (e > E - 1) e = E - 1;
        eidx[t] = e;
        int2 ii = *(const int2*)(edge_idx + 2 * e);
        cn[t] = ii.x; sn[t] = ii.y;
    }

    f32x4 acc[ET][4];
#pragma unroll
    for (int t = 0; t < ET; ++t)
#pragma unroll
        for (int m = 0; m < 4; ++m) acc[t][m] = 0.0f;

    // ---- layer 1: K = 192; all 12 B-loads of a subtile issued before use
#pragma unroll
    for (int t = 0; t < ET; ++t) {
        f32x4 raw[12];
#pragma unroll
        for (int s = 0; s < 6; ++s) {
            const float* src;
            if (s < 2)      src = edge_feat + (size_t)eidx[t] * 64 + s * 32 + a * 8;
            else if (s < 4) src = node_feat + (size_t)cn[t] * 64 + (s - 2) * 32 + a * 8;
            else            src = node_feat + (size_t)sn[t] * 64 + (s - 4) * 32 + a * 8;
            raw[2 * s]     = *(const f32x4*)src;
            raw[2 * s + 1] = *(const f32x4*)(src + 4);
        }
#pragma unroll
        for (int s = 0; s < 6; ++s) {
            bf16x8 bf = cvt2bf(raw[2 * s], raw[2 * s + 1]);
#pragma unroll
            for (int m = 0; m < 4; ++m) {
                bf16x8 af = *(const bf16x8*)(wlds + ((s * 4 + m) * 64 + lane) * 8);
                acc[t][m] = __builtin_amdgcn_mfma_f32_16x16x32_bf16(af, bf, acc[t][m], 0, 0, 0);
            }
        }
    }
    __syncthreads();   // everyone done with layer-1 weights
    // ---- re-stage: EW2 | EW3 (16 KB) into the same buffer
#pragma unroll
    for (int i = 0; i < 2; ++i) {
        int idx = i * 512 + tid;
        *(u32x4*)(wlds + (size_t)idx * 8) = *(const u32x4*)(Pw + PK_EW2 + (size_t)idx * 8);
    }
    __syncthreads();

    // ---- layers 2 & 3 per subtile (weights from LDS: L2 at 0, L3 at 4096)
#pragma unroll
    for (int t = 0; t < ET; ++t) {
        // bias + relu (layer1) -> tile
#pragma unroll
        for (int m = 0; m < 4; ++m) {
            float v0 = fmaxf(acc[t][m][0] + params[0][16 * m + 4 * a + 0], 0.0f);
            float v1 = fmaxf(acc[t][m][1] + params[0][16 * m + 4 * a + 1], 0.0f);
            float v2 = fmaxf(acc[t][m][2] + params[0][16 * m + 4 * a + 2], 0.0f);
            float v3 = fmaxf(acc[t][m][3] + params[0][16 * m + 4 * a + 3], 0.0f);
            u32x2 pv; pv[0] = pk2(v0, v1); pv[1] = pk2(v2, v3);
            int boff = (er * 128 + (16 * m + 4 * a) * 2) ^ swz;
            *(u32x2*)((char*)ht + boff) = pv;
        }
        // layer 2: K = 64
        f32x4 a2[4];
#pragma unroll
        for (int m = 0; m < 4; ++m) a2[m] = 0.0f;
#pragma unroll
        for (int s = 0; s < 2; ++s) {
            int boff = (er * 128 + s * 64 + a * 16) ^ swz;
            bf16x8 bf = *(const bf16x8*)((char*)ht + boff);
#pragma unroll
            for (int m = 0; m < 4; ++m) {
                bf16x8 af = *(const bf16x8*)(wlds + ((s * 4 + m) * 64 + lane) * 8);
                a2[m] = __builtin_amdgcn_mfma_f32_16x16x32_bf16(af, bf, a2[m], 0, 0, 0);
            }
        }
        // bias + relu (layer2) -> tile (same-wave DS ops are in-order)
#pragma unroll
        for (int m = 0; m < 4; ++m) {
            float v0 = fmaxf(a2[m][0] + params[1][16 * m + 4 * a + 0], 0.0f);
            float v1 = fmaxf(a2[m][1] + params[1][16 * m + 4 * a + 1], 0.0f);
            float v2 = fmaxf(a2[m][2] + params[1][16 * m + 4 * a + 2], 0.0f);
            float v3 = fmaxf(a2[m][3] + params[1][16 * m + 4 * a + 3], 0.0f);
            u32x2 pv; pv[0] = pk2(v0, v1); pv[1] = pk2(v2, v3);
            int boff = (er * 128 + (16 * m + 4 * a) * 2) ^ swz;
            *(u32x2*)((char*)ht + boff) = pv;
        }
        // layer 3: K = 64 (no relu)
        f32x4 a3[4];
#pragma unroll
        for (int m = 0; m < 4; ++m) a3[m] = 0.0f;
#pragma unroll
        for (int s = 0; s < 2; ++s) {
            int boff = (er * 128 + s * 64 + a * 16) ^ swz;
            bf16x8 bf = *(const bf16x8*)((char*)ht + boff);
#pragma unroll
            for (int m = 0; m < 4; ++m) {
                bf16x8 af = *(const bf16x8*)(wlds + 4096 + ((s * 4 + m) * 64 + lane) * 8);
                a3[m] = __builtin_amdgcn_mfma_f32_16x16x32_bf16(af, bf, a3[m], 0, 0, 0);
            }
        }
        // LayerNorm + store
        float vals[16], sum = 0.0f, ssq = 0.0f;
#pragma unroll
        for (int m = 0; m < 4; ++m)
#pragma unroll
            for (int r = 0; r < 4; ++r) {
                float v = a3[m][r] + params[2][16 * m + 4 * a + r];
                vals[4 * m + r] = v; sum += v; ssq += v * v;
            }
        sum += __shfl_xor(sum, 16, 64); sum += __shfl_xor(sum, 32, 64);
        ssq += __shfl_xor(ssq, 16, 64); ssq += __shfl_xor(ssq, 32, 64);
        const float mean = sum * 0.015625f;
        const float var = ssq * 0.015625f - mean * mean;
        const float inv = rsqrtf(var + 1e-5f);
        const int e = ebase + t * 16 + er;
        if (e < E) {
#pragma unroll
            for (int m = 0; m < 4; ++m) {
                f32x4 o;
#pragma unroll
                for (int r = 0; r < 4; ++r) {
                    int f = 16 * m + 4 * a + r;
                    o[r] = (vals[4 * m + r] - mean) * inv * params[3][f] + params[4][f];
                }
                *(f32x4*)(out_edge + (size_t)e * 64 + 16 * m + 4 * a) = o;
            }
        }
    }
}

// ---------------- node MLP + LN (nodal precomputed as bf16; linear reads) ----------------
__global__ __launch_bounds__(256) void node_mlp_kernel(
    const float* __restrict__ node_feat, const u16* __restrict__ nodal16,
    const u16* __restrict__ Pw,
    const float* __restrict__ b1g, const float* __restrict__ b2g, const float* __restrict__ b3g,
    const float* __restrict__ gg, const float* __restrict__ betag,
    float* __restrict__ out_node, int N)
{
    __shared__ float params[5][64];
    __shared__ u16 htile[4][1024];
    const int tid = threadIdx.x;
    if (tid < 64) {
        params[0][tid] = b1g[tid];
        params[1][tid] = b2g[tid];
        params[2][tid] = b3g[tid];
        params[3][tid] = gg[tid];
        params[4][tid] = betag[tid];
    }
    __syncthreads();
    const int wid = tid >> 6, lane = tid & 63;
    const int er = lane & 15, a = lane >> 4;
    const int nbase = (blockIdx.x * 4 + wid) * 16;
    if (nbase >= N) return;
    const int n = nbase + er;
    u16* ht = htile[wid];
    const int swz = (er & 7) << 4;

    f32x4 acc[4];
#pragma unroll
    for (int m = 0; m < 4; ++m) acc[m] = 0.0f;

    // ---- layer 1: K = 128 (concat: node_feat | nodal_edge_feat[bf16])
#pragma unroll
    for (int s = 0; s < 4; ++s) {
        bf16x8 af[4];
#pragma unroll
        for (int m = 0; m < 4; ++m)
            af[m] = *(const bf16x8*)(Pw + PK_NW1 + ((s * 4 + m) * 64 + lane) * 8);
        bf16x8 bf;
        if (s < 2) bf = load8f_bf(node_feat + (size_t)n * 64 + s * 32 + a * 8);
        else       bf = *(const bf16x8*)(nodal16 + (size_t)n * 64 + (s - 2) * 32 + a * 8);
#pragma unroll
        for (int m = 0; m < 4; ++m)
            acc[m] = __builtin_amdgcn_mfma_f32_16x16x32_bf16(af[m], bf, acc[m], 0, 0, 0);
    }
#pragma unroll
    for (int m = 0; m < 4; ++m) {
        float v0 = fmaxf(acc[m][0] + params[0][16 * m + 4 * a + 0], 0.0f);
        float v1 = fmaxf(acc[m][1] + params[0][16 * m + 4 * a + 1], 0.0f);
        float v2 = fmaxf(acc[m][2] + params[0][16 * m + 4 * a + 2], 0.0f);
        float v3 = fmaxf(acc[m][3] + params[0][16 * m + 4 * a + 3], 0.0f);
        u32x2 pv; pv[0] = pk2(v0, v1); pv[1] = pk2(v2, v3);
        int boff = (er * 128 + (16 * m + 4 * a) * 2) ^ swz;
        *(u32x2*)((char*)ht + boff) = pv;
    }

    // ---- layer 2
#pragma unroll
    for (int m = 0; m < 4; ++m) acc[m] = 0.0f;
#pragma unroll
    for (int s = 0; s < 2; ++s) {
        bf16x8 af[4];
#pragma unroll
        for (int m = 0; m < 4; ++m)
            af[m] = *(const bf16x8*)(Pw + PK_NW2 + ((s * 4 + m) * 64 + lane) * 8);
        int boff = (er * 128 + s * 64 + a * 16) ^ swz;
        bf16x8 bf = *(const bf16x8*)((char*)ht + boff);
#pragma unroll
        for (int m = 0; m < 4; ++m)
            acc[m] = __builtin_amdgcn_mfma_f32_16x16x32_bf16(af[m], bf, acc[m], 0, 0, 0);
    }
#pragma unroll
    for (int m = 0; m < 4; ++m) {
        float v0 = fmaxf(acc[m][0] + params[1][16 * m + 4 * a + 0], 0.0f);
        float v1 = fmaxf(acc[m][1] + params[1][16 * m + 4 * a + 1], 0.0f);
        float v2 = fmaxf(acc[m][2] + params[1][16 * m + 4 * a + 2], 0.0f);
        float v3 = fmaxf(acc[m][3] + params[1][16 * m + 4 * a + 3], 0.0f);
        u32x2 pv; pv[0] = pk2(v0, v1); pv[1] = pk2(v2, v3);
        int boff = (er * 128 + (16 * m + 4 * a) * 2) ^ swz;
        *(u32x2*)((char*)ht + boff) = pv;
    }

    // ---- layer 3 + LN
#pragma unroll
    for (int m = 0; m < 4; ++m) acc[m] = 0.0f;
#pragma unroll
    for (int s = 0; s < 2; ++s) {
        bf16x8 af[4];
#pragma unroll
        for (int m = 0; m < 4; ++m)
            af[m] = *(const bf16x8*)(Pw + PK_NW3 + ((s * 4 + m) * 64 + lane) * 8);
        int boff = (er * 128 + s * 64 + a * 16) ^ swz;
        bf16x8 bf = *(const bf16x8*)((char*)ht + boff);
#pragma unroll
        for (int m = 0; m < 4; ++m)
            acc[m] = __builtin_amdgcn_mfma_f32_16x16x32_bf16(af[m], bf, acc[m], 0, 0, 0);
    }
    float vals[16], sum = 0.0f, ssq = 0.0f;
#pragma unroll
    for (int m = 0; m < 4; ++m)
#pragma unroll
        for (int r = 0; r < 4; ++r) {
            float v = acc[m][r] + params[2][16 * m + 4 * a + r];
            vals[4 * m + r] = v; sum += v; ssq += v * v;
        }
    sum += __shfl_xor(sum, 16, 64); sum += __shfl_xor(sum, 32, 64);
    ssq += __shfl_xor(ssq, 16, 64); ssq += __shfl_xor(ssq, 32, 64);
    const float mean = sum * 0.015625f;
    const float var = ssq * 0.015625f - mean * mean;
    const float inv = rsqrtf(var + 1e-5f);
#pragma unroll
    for (int m = 0; m < 4; ++m) {
        f32x4 o;
#pragma unroll
        for (int r = 0; r < 4; ++r) {
            int f = 16 * m + 4 * a + r;
            o[r] = (vals[4 * m + r] - mean) * inv * params[3][f] + params[4][f];
        }
        *(f32x4*)(out_node + (size_t)n * 64 + 16 * m + 4 * a) = o;
    }
}

extern "C" void kernel_launch(void* const* d_in, const int* in_sizes, int n_in,
                              void* d_out, int out_size, void* d_ws, size_t ws_size,
                              hipStream_t stream) {
    const float* node_feat = (const float*)d_in[0];
    const float* edge_feat = (const float*)d_in[1];
    const int* edge_idx  = (const int*)d_in[2];
    const float* eW1 = (const float*)d_in[4];
    const float* eb1 = (const float*)d_in[5];
    const float* eW2 = (const float*)d_in[6];
    const float* eb2 = (const float*)d_in[7];
    const float* eW3 = (const float*)d_in[8];
    const float* eb3 = (const float*)d_in[9];
    const float* eg  = (const float*)d_in[10];
    const float* ebt = (const float*)d_in[11];
    const float* nW1 = (const float*)d_in[12];
    const float* nb1 = (const float*)d_in[13];
    const float* nW2 = (const float*)d_in[14];
    const float* nb2 = (const float*)d_in[15];
    const float* nW3 = (const float*)d_in[16];
    const float* nb3 = (const float*)d_in[17];
    const float* ng  = (const float*)d_in[18];
    const float* nbt = (const float*)d_in[19];

    const int N = in_sizes[0] / 64;
    const int E = in_sizes[1] / 64;
    const int nparts = (N + 255) / 256;

    // ws layout
    char* w = (char*)d_ws;
    int* off      = (int*)w;                    w += (size_t)(N + 1) * 4;
    int* pos      = (int*)w;                    w += (size_t)N * 4;
    int* partials = (int*)w;                    w += 256 * 4;
    int* csr      = (int*)w;                    w += (size_t)E * 4;
    u16* Pw       = (u16*)w;                    w += (size_t)PK_TOTAL * 2;
    u16* nodal16  = (u16*)w;                    // N*64 bf16

    float* out_edge = (float*)d_out;
    float* out_node = out_edge + (size_t)E * 64;

    pack_weights_kernel<<<(PK_TOTAL + 255) / 256, 256, 0, stream>>>(eW1, eW2, eW3, nW1, nW2, nW3, Pw);

    // big streaming kernel first (512 threads, 256 edges per block)
    const int eblocks = (E + 255) / 256;
    edge_mlp_kernel<<<eblocks, 512, 0, stream>>>(node_feat, edge_feat, edge_idx, Pw,
                                                 eb1, eb2, eb3, eg, ebt, out_edge, E);

    // CSR build (pos doubles as degree histogram)
    hipMemsetAsync(pos, 0, (size_t)N * 4, stream);
    degree_kernel<<<(E + 255) / 256, 256, 0, stream>>>(edge_idx, pos, E);
    scan_blocks_kernel<<<nparts, 256, 0, stream>>>(pos, off, partials, N);
    scan_partials_kernel<<<1, 256, 0, stream>>>(partials, nparts);
    finalize_offsets_kernel<<<(N + 255) / 256, 256, 0, stream>>>(off, pos, partials, N, E);
    fill_csr_kernel<<<(E + 255) / 256, 256, 0, stream>>>(edge_idx, pos, csr, E);

    // wide segment-sum gather (one wave per node)
    gather_kernel<<<(N + 3) / 4, 256, 0, stream>>>(out_edge, off, csr, nodal16, N);

    const int nblocks = (N + 63) / 64;
    node_mlp_kernel<<<nblocks, 256, 0, stream>>>(node_feat, nodal16, Pw,
                                                 nb1, nb2, nb3, ng, nbt, out_node, N);
}

// Round 8
// 558.664 us; speedup vs baseline: 1.1600x; 1.0214x over previous
//
#include <hip/hip_runtime.h>

typedef unsigned short u16;
typedef unsigned int u32;
typedef __attribute__((ext_vector_type(8))) __bf16 bf16x8;
typedef __attribute__((ext_vector_type(4))) float f32x4;
typedef __attribute__((ext_vector_type(2))) u32 u32x2;
typedef __attribute__((ext_vector_type(4))) u32 u32x4;

__device__ __forceinline__ u16 f2bf(float f) {
    u32 u = __float_as_uint(f);
    u = (u + 0x7FFFu + ((u >> 16) & 1u)) >> 16;
    return (u16)u;
}
__device__ __forceinline__ float bf2f(u16 h) {
    return __uint_as_float(((u32)h) << 16);
}
__device__ __forceinline__ bf16x8 cvt2bf(f32x4 lo, f32x4 hi) {
    bf16x8 r;
    r[0] = (__bf16)lo[0]; r[1] = (__bf16)lo[1]; r[2] = (__bf16)lo[2]; r[3] = (__bf16)lo[3];
    r[4] = (__bf16)hi[0]; r[5] = (__bf16)hi[1]; r[6] = (__bf16)hi[2]; r[7] = (__bf16)hi[3];
    return r;
}
__device__ __forceinline__ bf16x8 load8f_bf(const float* p) {
    return cvt2bf(*(const f32x4*)p, *(const f32x4*)(p + 4));
}
__device__ __forceinline__ u32 pk2(float x, float y) {
    __bf16 bx = (__bf16)x, by = (__bf16)y;
    return (u32)__builtin_bit_cast(u16, bx) | ((u32)__builtin_bit_cast(u16, by) << 16);
}

// packed A-fragment (W^T) layout, per layer: idx = ((s*4 + m)*64 + lane)*8 + j
// value = W[k][16*m + (lane&15)], k = s*32 + (lane>>4)*8 + j
#define PK_EW1 0
#define PK_EW2 12288
#define PK_EW3 16384
#define PK_NW1 20480
#define PK_NW2 28672
#define PK_NW3 32768
#define PK_TOTAL 36864

__global__ void pack_weights_kernel(const float* __restrict__ eW1, const float* __restrict__ eW2,
                                    const float* __restrict__ eW3, const float* __restrict__ nW1,
                                    const float* __restrict__ nW2, const float* __restrict__ nW3,
                                    u16* __restrict__ P) {
    int idx = blockIdx.x * blockDim.x + threadIdx.x;
    if (idx >= PK_TOTAL) return;
    const float* W; int base;
    if (idx < PK_EW2)      { W = eW1; base = PK_EW1; }
    else if (idx < PK_EW3) { W = eW2; base = PK_EW2; }
    else if (idx < PK_NW1) { W = eW3; base = PK_EW3; }
    else if (idx < PK_NW2) { W = nW1; base = PK_NW1; }
    else if (idx < PK_NW3) { W = nW2; base = PK_NW2; }
    else                   { W = nW3; base = PK_NW3; }
    int r = idx - base;
    int j = r & 7, lane = (r >> 3) & 63, m = (r >> 9) & 3, s = r >> 11;
    int k = s * 32 + (lane >> 4) * 8 + j;
    int col = 16 * m + (lane & 15);
    P[idx] = f2bf(W[k * 64 + col]);
}

// ---------------- CSR build ----------------
__global__ void degree_kernel(const int* __restrict__ edge_idx, int* __restrict__ deg, int E) {
    int e = blockIdx.x * blockDim.x + threadIdx.x;
    if (e < E) atomicAdd(&deg[edge_idx[2 * e]], 1);
}

__global__ void scan_blocks_kernel(const int* __restrict__ deg, int* __restrict__ off,
                                   int* __restrict__ partials, int N) {
    __shared__ int sh[256];
    const int t = threadIdx.x;
    const int g = blockIdx.x * 256 + t;
    int v = (g < N) ? deg[g] : 0;
    sh[t] = v;
    __syncthreads();
#pragma unroll
    for (int d = 1; d < 256; d <<= 1) {
        int add = (t >= d) ? sh[t - d] : 0;
        __syncthreads();
        sh[t] += add;
        __syncthreads();
    }
    if (g < N) off[g] = sh[t] - v;
    if (t == 255) partials[blockIdx.x] = sh[255];
}

__global__ void scan_partials_kernel(int* __restrict__ partials, int nparts) {
    __shared__ int sh[256];
    const int t = threadIdx.x;
    int v = (t < nparts) ? partials[t] : 0;
    sh[t] = v;
    __syncthreads();
#pragma unroll
    for (int d = 1; d < 256; d <<= 1) {
        int add = (t >= d) ? sh[t - d] : 0;
        __syncthreads();
        sh[t] += add;
        __syncthreads();
    }
    if (t < nparts) partials[t] = sh[t] - v;
}

__global__ void finalize_offsets_kernel(int* __restrict__ off, int* __restrict__ pos,
                                        const int* __restrict__ partials, int N, int E) {
    int g = blockIdx.x * blockDim.x + threadIdx.x;
    if (g < N) {
        int o = off[g] + partials[g >> 8];
        off[g] = o;
        pos[g] = o;
    }
    if (g == 0) off[N] = E;
}

__global__ void fill_csr_kernel(const int* __restrict__ edge_idx, int* __restrict__ pos,
                                int* __restrict__ csr, int E) {
    int e = blockIdx.x * blockDim.x + threadIdx.x;
    if (e < E) {
        int slot = atomicAdd(&pos[edge_idx[2 * e]], 1);
        csr[slot] = e;
    }
}

// ---------------- edge MLP + LN + fused segment-sum (CSR-ordered) ----------------
#define ET 2
__global__ __launch_bounds__(512, 6) void edge_mlp_kernel(
    const float* __restrict__ node_feat, const float* __restrict__ edge_feat,
    const int* __restrict__ edge_idx, const int* __restrict__ csr,
    const u16* __restrict__ Pw,
    const float* __restrict__ b1g, const float* __restrict__ b2g, const float* __restrict__ b3g,
    const float* __restrict__ gg, const float* __restrict__ betag,
    float* __restrict__ out_edge, float* __restrict__ nodal, int E)
{
    __shared__ u16 wlds[12288];     // 24 KB: phase A = EW1; phase B = EW2|EW3
    __shared__ u16 htile[8][1024];  // per-wave 16x64 bf16 tile, XOR-swizzled
    __shared__ int cnt[8][16];      // per-wave center ids of the current subtile
    __shared__ float params[5][64];
    const int tid = threadIdx.x;
    // ---- stage layer-1 weights (24 KB)
#pragma unroll
    for (int i = 0; i < 3; ++i) {
        int idx = i * 512 + tid;
        *(u32x4*)(wlds + (size_t)idx * 8) = *(const u32x4*)(Pw + PK_EW1 + (size_t)idx * 8);
    }
    if (tid < 64) {
        params[0][tid] = b1g[tid];
        params[1][tid] = b2g[tid];
        params[2][tid] = b3g[tid];
        params[3][tid] = gg[tid];
        params[4][tid] = betag[tid];
    }
    __syncthreads();

    const int wid = tid >> 6, lane = tid & 63;
    const int er = lane & 15, a = lane >> 4;
    const int sbase = (blockIdx.x * 8 + wid) * (16 * ET);   // slot base (E % 256 == 0)
    u16* ht = htile[wid];
    const int swz = (er & 7) << 4;

    int eidx[ET], cn[ET], sn[ET];
#pragma unroll
    for (int t = 0; t < ET; ++t) {
        int slot = sbase + t * 16 + er;
        if (slot > E - 1) slot = E - 1;
        int e = csr[slot];
        eidx[t] = e;
        int2 ii = *(const int2*)(edge_idx + 2 * e);
        cn[t] = ii.x; sn[t] = ii.y;
    }

    f32x4 acc[ET][4];
#pragma unroll
    for (int t = 0; t < ET; ++t)
#pragma unroll
        for (int m = 0; m < 4; ++m) acc[t][m] = 0.0f;

    // ---- layer 1: K = 192; all 12 B-loads of a subtile issued before use
#pragma unroll
    for (int t = 0; t < ET; ++t) {
        f32x4 raw[12];
#pragma unroll
        for (int s = 0; s < 6; ++s) {
            const float* src;
            if (s < 2)      src = edge_feat + (size_t)eidx[t] * 64 + s * 32 + a * 8;
            else if (s < 4) src = node_feat + (size_t)cn[t] * 64 + (s - 2) * 32 + a * 8;
            else            src = node_feat + (size_t)sn[t] * 64 + (s - 4) * 32 + a * 8;
            raw[2 * s]     = *(const f32x4*)src;
            raw[2 * s + 1] = *(const f32x4*)(src + 4);
        }
#pragma unroll
        for (int s = 0; s < 6; ++s) {
            bf16x8 bf = cvt2bf(raw[2 * s], raw[2 * s + 1]);
#pragma unroll
            for (int m = 0; m < 4; ++m) {
                bf16x8 af = *(const bf16x8*)(wlds + ((s * 4 + m) * 64 + lane) * 8);
                acc[t][m] = __builtin_amdgcn_mfma_f32_16x16x32_bf16(af, bf, acc[t][m], 0, 0, 0);
            }
        }
    }
    __syncthreads();   // everyone done with layer-1 weights
    // ---- re-stage: EW2 | EW3 (16 KB) into the same buffer
#pragma unroll
    for (int i = 0; i < 2; ++i) {
        int idx = i * 512 + tid;
        *(u32x4*)(wlds + (size_t)idx * 8) = *(const u32x4*)(Pw + PK_EW2 + (size_t)idx * 8);
    }
    __syncthreads();

    // ---- layers 2 & 3 per subtile (weights from LDS: L2 at 0, L3 at 4096)
#pragma unroll
    for (int t = 0; t < ET; ++t) {
        // bias + relu (layer1) -> tile
#pragma unroll
        for (int m = 0; m < 4; ++m) {
            float v0 = fmaxf(acc[t][m][0] + params[0][16 * m + 4 * a + 0], 0.0f);
            float v1 = fmaxf(acc[t][m][1] + params[0][16 * m + 4 * a + 1], 0.0f);
            float v2 = fmaxf(acc[t][m][2] + params[0][16 * m + 4 * a + 2], 0.0f);
            float v3 = fmaxf(acc[t][m][3] + params[0][16 * m + 4 * a + 3], 0.0f);
            u32x2 pv; pv[0] = pk2(v0, v1); pv[1] = pk2(v2, v3);
            int boff = (er * 128 + (16 * m + 4 * a) * 2) ^ swz;
            *(u32x2*)((char*)ht + boff) = pv;
        }
        // layer 2: K = 64
        f32x4 a2[4];
#pragma unroll
        for (int m = 0; m < 4; ++m) a2[m] = 0.0f;
#pragma unroll
        for (int s = 0; s < 2; ++s) {
            int boff = (er * 128 + s * 64 + a * 16) ^ swz;
            bf16x8 bf = *(const bf16x8*)((char*)ht + boff);
#pragma unroll
            for (int m = 0; m < 4; ++m) {
                bf16x8 af = *(const bf16x8*)(wlds + ((s * 4 + m) * 64 + lane) * 8);
                a2[m] = __builtin_amdgcn_mfma_f32_16x16x32_bf16(af, bf, a2[m], 0, 0, 0);
            }
        }
        // bias + relu (layer2) -> tile (same-wave DS ops are in-order)
#pragma unroll
        for (int m = 0; m < 4; ++m) {
            float v0 = fmaxf(a2[m][0] + params[1][16 * m + 4 * a + 0], 0.0f);
            float v1 = fmaxf(a2[m][1] + params[1][16 * m + 4 * a + 1], 0.0f);
            float v2 = fmaxf(a2[m][2] + params[1][16 * m + 4 * a + 2], 0.0f);
            float v3 = fmaxf(a2[m][3] + params[1][16 * m + 4 * a + 3], 0.0f);
            u32x2 pv; pv[0] = pk2(v0, v1); pv[1] = pk2(v2, v3);
            int boff = (er * 128 + (16 * m + 4 * a) * 2) ^ swz;
            *(u32x2*)((char*)ht + boff) = pv;
        }
        // layer 3: K = 64 (no relu)
        f32x4 a3[4];
#pragma unroll
        for (int m = 0; m < 4; ++m) a3[m] = 0.0f;
#pragma unroll
        for (int s = 0; s < 2; ++s) {
            int boff = (er * 128 + s * 64 + a * 16) ^ swz;
            bf16x8 bf = *(const bf16x8*)((char*)ht + boff);
#pragma unroll
            for (int m = 0; m < 4; ++m) {
                bf16x8 af = *(const bf16x8*)(wlds + 4096 + ((s * 4 + m) * 64 + lane) * 8);
                a3[m] = __builtin_amdgcn_mfma_f32_16x16x32_bf16(af, bf, a3[m], 0, 0, 0);
            }
        }
        // LayerNorm
        float vals[16], sum = 0.0f, ssq = 0.0f;
#pragma unroll
        for (int m = 0; m < 4; ++m)
#pragma unroll
            for (int r = 0; r < 4; ++r) {
                float v = a3[m][r] + params[2][16 * m + 4 * a + r];
                vals[4 * m + r] = v; sum += v; ssq += v * v;
            }
        sum += __shfl_xor(sum, 16, 64); sum += __shfl_xor(sum, 32, 64);
        ssq += __shfl_xor(ssq, 16, 64); ssq += __shfl_xor(ssq, 32, 64);
        const float mean = sum * 0.015625f;
        const float var = ssq * 0.015625f - mean * mean;
        const float inv = rsqrtf(var + 1e-5f);
        const int slot = sbase + t * 16 + er;
        const int e = eidx[t];
        // store to out_edge (scattered full 256B rows) + bf16 LN tile + center ids
#pragma unroll
        for (int m = 0; m < 4; ++m) {
            f32x4 o;
#pragma unroll
            for (int r = 0; r < 4; ++r) {
                int f = 16 * m + 4 * a + r;
                o[r] = (vals[4 * m + r] - mean) * inv * params[3][f] + params[4][f];
            }
            if (slot < E)
                *(f32x4*)(out_edge + (size_t)e * 64 + 16 * m + 4 * a) = o;
            u32x2 pv; pv[0] = pk2(o[0], o[1]); pv[1] = pk2(o[2], o[3]);
            int boff = (er * 128 + (16 * m + 4 * a) * 2) ^ swz;
            *(u32x2*)((char*)ht + boff) = pv;
        }
        if (a == 0) cnt[wid][er] = (slot < E) ? cn[t] : -1;
        // ---- in-wave segmented reduce over the 16 edge-rows, flush per center-run
        {
            const int f = lane;                 // feature 0..63
            float accv = 0.0f;
            int cprev = cnt[wid][0];
#pragma unroll
            for (int er2 = 0; er2 < 16; ++er2) {
                int c = cnt[wid][er2];
                if (c != cprev) {
                    if (cprev >= 0) unsafeAtomicAdd(nodal + (size_t)cprev * 64 + f, accv);
                    accv = 0.0f; cprev = c;
                }
                int boff = (er2 * 128 + f * 2) ^ ((er2 & 7) << 4);
                accv += bf2f(*(const u16*)((char*)ht + boff));
            }
            if (cprev >= 0) unsafeAtomicAdd(nodal + (size_t)cprev * 64 + f, accv);
        }
    }
}

// ---------------- node MLP + LN (nodal fp32; linear reads) ----------------
__global__ __launch_bounds__(256) void node_mlp_kernel(
    const float* __restrict__ node_feat, const float* __restrict__ nodal,
    const u16* __restrict__ Pw,
    const float* __restrict__ b1g, const float* __restrict__ b2g, const float* __restrict__ b3g,
    const float* __restrict__ gg, const float* __restrict__ betag,
    float* __restrict__ out_node, int N)
{
    __shared__ float params[5][64];
    __shared__ u16 htile[4][1024];
    const int tid = threadIdx.x;
    if (tid < 64) {
        params[0][tid] = b1g[tid];
        params[1][tid] = b2g[tid];
        params[2][tid] = b3g[tid];
        params[3][tid] = gg[tid];
        params[4][tid] = betag[tid];
    }
    __syncthreads();
    const int wid = tid >> 6, lane = tid & 63;
    const int er = lane & 15, a = lane >> 4;
    const int nbase = (blockIdx.x * 4 + wid) * 16;
    if (nbase >= N) return;
    const int n = nbase + er;
    u16* ht = htile[wid];
    const int swz = (er & 7) << 4;

    f32x4 acc[4];
#pragma unroll
    for (int m = 0; m < 4; ++m) acc[m] = 0.0f;

    // ---- layer 1: K = 128 (concat: node_feat | nodal_edge_feat fp32)
#pragma unroll
    for (int s = 0; s < 4; ++s) {
        bf16x8 af[4];
#pragma unroll
        for (int m = 0; m < 4; ++m)
            af[m] = *(const bf16x8*)(Pw + PK_NW1 + ((s * 4 + m) * 64 + lane) * 8);
        bf16x8 bf;
        if (s < 2) bf = load8f_bf(node_feat + (size_t)n * 64 + s * 32 + a * 8);
        else       bf = load8f_bf(nodal + (size_t)n * 64 + (s - 2) * 32 + a * 8);
#pragma unroll
        for (int m = 0; m < 4; ++m)
            acc[m] = __builtin_amdgcn_mfma_f32_16x16x32_bf16(af[m], bf, acc[m], 0, 0, 0);
    }
#pragma unroll
    for (int m = 0; m < 4; ++m) {
        float v0 = fmaxf(acc[m][0] + params[0][16 * m + 4 * a + 0], 0.0f);
        float v1 = fmaxf(acc[m][1] + params[0][16 * m + 4 * a + 1], 0.0f);
        float v2 = fmaxf(acc[m][2] + params[0][16 * m + 4 * a + 2], 0.0f);
        float v3 = fmaxf(acc[m][3] + params[0][16 * m + 4 * a + 3], 0.0f);
        u32x2 pv; pv[0] = pk2(v0, v1); pv[1] = pk2(v2, v3);
        int boff = (er * 128 + (16 * m + 4 * a) * 2) ^ swz;
        *(u32x2*)((char*)ht + boff) = pv;
    }

    // ---- layer 2
#pragma unroll
    for (int m = 0; m < 4; ++m) acc[m] = 0.0f;
#pragma unroll
    for (int s = 0; s < 2; ++s) {
        bf16x8 af[4];
#pragma unroll
        for (int m = 0; m < 4; ++m)
            af[m] = *(const bf16x8*)(Pw + PK_NW2 + ((s * 4 + m) * 64 + lane) * 8);
        int boff = (er * 128 + s * 64 + a * 16) ^ swz;
        bf16x8 bf = *(const bf16x8*)((char*)ht + boff);
#pragma unroll
        for (int m = 0; m < 4; ++m)
            acc[m] = __builtin_amdgcn_mfma_f32_16x16x32_bf16(af[m], bf, acc[m], 0, 0, 0);
    }
#pragma unroll
    for (int m = 0; m < 4; ++m) {
        float v0 = fmaxf(acc[m][0] + params[1][16 * m + 4 * a + 0], 0.0f);
        float v1 = fmaxf(acc[m][1] + params[1][16 * m + 4 * a + 1], 0.0f);
        float v2 = fmaxf(acc[m][2] + params[1][16 * m + 4 * a + 2], 0.0f);
        float v3 = fmaxf(acc[m][3] + params[1][16 * m + 4 * a + 3], 0.0f);
        u32x2 pv; pv[0] = pk2(v0, v1); pv[1] = pk2(v2, v3);
        int boff = (er * 128 + (16 * m + 4 * a) * 2) ^ swz;
        *(u32x2*)((char*)ht + boff) = pv;
    }

    // ---- layer 3 + LN
#pragma unroll
    for (int m = 0; m < 4; ++m) acc[m] = 0.0f;
#pragma unroll
    for (int s = 0; s < 2; ++s) {
        bf16x8 af[4];
#pragma unroll
        for (int m = 0; m < 4; ++m)
            af[m] = *(const bf16x8*)(Pw + PK_NW3 + ((s * 4 + m) * 64 + lane) * 8);
        int boff = (er * 128 + s * 64 + a * 16) ^ swz;
        bf16x8 bf = *(const bf16x8*)((char*)ht + boff);
#pragma unroll
        for (int m = 0; m < 4; ++m)
            acc[m] = __builtin_amdgcn_mfma_f32_16x16x32_bf16(af[m], bf, acc[m], 0, 0, 0);
    }
    float vals[16], sum = 0.0f, ssq = 0.0f;
#pragma unroll
    for (int m = 0; m < 4; ++m)
#pragma unroll
        for (int r = 0; r < 4; ++r) {
            float v = acc[m][r] + params[2][16 * m + 4 * a + r];
            vals[4 * m + r] = v; sum += v; ssq += v * v;
        }
    sum += __shfl_xor(sum, 16, 64); sum += __shfl_xor(sum, 32, 64);
    ssq += __shfl_xor(ssq, 16, 64); ssq += __shfl_xor(ssq, 32, 64);
    const float mean = sum * 0.015625f;
    const float var = ssq * 0.015625f - mean * mean;
    const float inv = rsqrtf(var + 1e-5f);
#pragma unroll
    for (int m = 0; m < 4; ++m) {
        f32x4 o;
#pragma unroll
        for (int r = 0; r < 4; ++r) {
            int f = 16 * m + 4 * a + r;
            o[r] = (vals[4 * m + r] - mean) * inv * params[3][f] + params[4][f];
        }
        *(f32x4*)(out_node + (size_t)n * 64 + 16 * m + 4 * a) = o;
    }
}

extern "C" void kernel_launch(void* const* d_in, const int* in_sizes, int n_in,
                              void* d_out, int out_size, void* d_ws, size_t ws_size,
                              hipStream_t stream) {
    const float* node_feat = (const float*)d_in[0];
    const float* edge_feat = (const float*)d_in[1];
    const int* edge_idx  = (const int*)d_in[2];
    const float* eW1 = (const float*)d_in[4];
    const float* eb1 = (const float*)d_in[5];
    const float* eW2 = (const float*)d_in[6];
    const float* eb2 = (const float*)d_in[7];
    const float* eW3 = (const float*)d_in[8];
    const float* eb3 = (const float*)d_in[9];
    const float* eg  = (const float*)d_in[10];
    const float* ebt = (const float*)d_in[11];
    const float* nW1 = (const float*)d_in[12];
    const float* nb1 = (const float*)d_in[13];
    const float* nW2 = (const float*)d_in[14];
    const float* nb2 = (const float*)d_in[15];
    const float* nW3 = (const float*)d_in[16];
    const float* nb3 = (const float*)d_in[17];
    const float* ng  = (const float*)d_in[18];
    const float* nbt = (const float*)d_in[19];

    const int N = in_sizes[0] / 64;
    const int E = in_sizes[1] / 64;
    const int nparts = (N + 255) / 256;

    // ws layout
    char* w = (char*)d_ws;
    int* off      = (int*)w;                    w += (size_t)(N + 1) * 4;
    int* pos      = (int*)w;                    w += (size_t)N * 4;
    int* partials = (int*)w;                    w += 256 * 4;
    int* csr      = (int*)w;                    w += (size_t)E * 4;
    u16* Pw       = (u16*)w;                    w += (size_t)PK_TOTAL * 2;
    w = (char*)(((size_t)w + 255) & ~(size_t)255);
    float* nodal  = (float*)w;                  // N*64 fp32 segment sums

    float* out_edge = (float*)d_out;
    float* out_node = out_edge + (size_t)E * 64;

    pack_weights_kernel<<<(PK_TOTAL + 255) / 256, 256, 0, stream>>>(eW1, eW2, eW3, nW1, nW2, nW3, Pw);

    // CSR build first (edge kernel consumes csr)
    hipMemsetAsync(pos, 0, (size_t)N * 4, stream);
    hipMemsetAsync(nodal, 0, (size_t)N * 64 * 4, stream);
    degree_kernel<<<(E + 255) / 256, 256, 0, stream>>>(edge_idx, pos, E);
    scan_blocks_kernel<<<nparts, 256, 0, stream>>>(pos, off, partials, N);
    scan_partials_kernel<<<1, 256, 0, stream>>>(partials, nparts);
    finalize_offsets_kernel<<<(N + 255) / 256, 256, 0, stream>>>(off, pos, partials, N, E);
    fill_csr_kernel<<<(E + 255) / 256, 256, 0, stream>>>(edge_idx, pos, csr, E);

    // fused edge MLP + LN + segment-sum (CSR order)
    const int eblocks = (E + 255) / 256;
    edge_mlp_kernel<<<eblocks, 512, 0, stream>>>(node_feat, edge_feat, edge_idx, csr, Pw,
                                                 eb1, eb2, eb3, eg, ebt, out_edge, nodal, E);

    const int nblocks = (N + 63) / 64;
    node_mlp_kernel<<<nblocks, 256, 0, stream>>>(node_feat, nodal, Pw,
                                                 nb1, nb2, nb3, ng, nbt, out_node, N);
}